// Round 3
// baseline (2446.559 us; speedup 1.0000x reference)
//
#include <hip/hip_runtime.h>
#include <math.h>

// LSTM B=256, T=2048, D=H=64, OUT=8, fp32. One block per batch row.
// Round-3 key change: operand BROADCAST via v_readlane -> SGPR (per-SIMD
// VALU pipe, parallel across 4 waves) instead of per-lane LDS b128 reads
// (shared per-CU LDS pipe, 1536 cyc/step == round-2's measured bound).
// h[j] lives in lane j of every wave (replicated update) -> readlane from
// register, no LDS round-trip. x staged per-64-step chunk into LDS via
// global_load_lds, lifted with ONE ds_read_b128/wave/step (lanes 0-15
// hold the 64 values), then readlane'd with immediate lane indices.

#define Hh 64
#define Tt 2048
#define Bb 256
#define OUTN 8
#define CHUNK 64
#define NCHUNK (Tt / CHUNK)

typedef float floatx4 __attribute__((ext_vector_type(4)));

__device__ __forceinline__ float rlane(float v, int l) {
    return __builtin_bit_cast(float,
        __builtin_amdgcn_readlane(__builtin_bit_cast(int, v), l));
}

__device__ __forceinline__ float sigm(float z) {
    return 1.0f / (1.0f + __expf(-z));
}
__device__ __forceinline__ float tanh_s(float z) {   // overflow-safe tanh
    float e = __expf(2.0f * fabsf(z));
    float r = 1.0f - 2.0f / (e + 1.0f);
    return (z < 0.0f) ? -r : r;
}

__global__ __launch_bounds__(256, 1)
void lstm_fused_kernel(const float* __restrict__ x,
                       const float* __restrict__ w_ih,
                       const float* __restrict__ w_hh,
                       const float* __restrict__ b_ih,
                       const float* __restrict__ b_hh,
                       const float* __restrict__ fc_w,
                       const float* __restrict__ fc_b,
                       float* __restrict__ out)
{
    __shared__ __align__(16) float xch[2][CHUNK * Hh];  // 2 x 16 KB x-chunks
    __shared__ float gate_s[2][4 * Hh];                 // dbl-buffered gates

    const int tid  = threadIdx.x;    // gate index 0..255
    const int b    = blockIdx.x;     // batch row
    const int wave = tid >> 6;       // 0:i 1:f 2:g 3:o
    const int lane = tid & 63;       // hidden index

    const float* xb = x + (size_t)b * Tt * Hh;   // D == H == 64

    // ---- weight rows -> registers (pinned; AGPR placement acceptable) ----
    floatx4 wih4[16], whh4[16];
    {
        const floatx4* p = (const floatx4*)(w_ih + (size_t)tid * Hh);
        const floatx4* q = (const floatx4*)(w_hh + (size_t)tid * Hh);
        #pragma unroll
        for (int k = 0; k < 16; ++k) { wih4[k] = p[k]; whh4[k] = q[k]; }
        #pragma unroll
        for (int k = 0; k < 16; ++k) {
            asm volatile("" : "+v"(wih4[k]), "+v"(whh4[k]));
        }
    }
    const float bias = b_ih[tid] + b_hh[tid];

    // ---- stage chunk 0 into LDS (async, drained by first barrier) ----
    #pragma unroll
    for (int p4 = 0; p4 < 4; ++p4) {
        __builtin_amdgcn_global_load_lds(
            (const __attribute__((address_space(1))) void*)(xb + p4 * 1024 + tid * 4),
            (__attribute__((address_space(3))) void*)(&xch[0][p4 * 1024 + tid * 4]),
            16, 0, 0);
    }

    float hreg = 0.0f;   // lane j holds h[j] (replicated in all waves)
    float c    = 0.0f;   // lane j holds c[j]
    __syncthreads();

    for (int cc = 0; cc < NCHUNK; ++cc) {
        if (cc + 1 < NCHUNK) {       // async-stage next chunk
            const float* src = xb + (size_t)(cc + 1) * CHUNK * Hh;
            float* dst = &xch[(cc + 1) & 1][0];
            #pragma unroll
            for (int p4 = 0; p4 < 4; ++p4) {
                __builtin_amdgcn_global_load_lds(
                    (const __attribute__((address_space(1))) void*)(src + p4 * 1024 + tid * 4),
                    (__attribute__((address_space(3))) void*)(dst + p4 * 1024 + tid * 4),
                    16, 0, 0);
            }
        }
        const float* xcbuf = &xch[cc & 1][0];

        for (int s = 0; s < CHUNK; ++s) {
            // lift x_t into VGPRs: lane L holds x[s][4*(L&15)+j] in xv[j]
            floatx4 xv = *(const floatx4*)(xcbuf + s * Hh + (lane & 15) * 4);

            // z = bias + w_hh[g].h + w_ih[g].x  -- operands broadcast via
            // readlane (imm lane idx), weights from registers, 4 acc chains
            float a0 = 0.f, a1 = 0.f, a2 = 0.f, a3 = 0.f;
            #pragma unroll
            for (int k = 0; k < 16; ++k) {
                floatx4 w = whh4[k];
                a0 += rlane(hreg, 4 * k + 0) * w[0];
                a1 += rlane(hreg, 4 * k + 1) * w[1];
                a2 += rlane(hreg, 4 * k + 2) * w[2];
                a3 += rlane(hreg, 4 * k + 3) * w[3];
            }
            #pragma unroll
            for (int k = 0; k < 16; ++k) {
                floatx4 w = wih4[k];
                a0 += rlane(xv[0], k) * w[0];   // x[s][4k+0]
                a1 += rlane(xv[1], k) * w[1];   // x[s][4k+1]
                a2 += rlane(xv[2], k) * w[2];   // x[s][4k+2]
                a3 += rlane(xv[3], k) * w[3];   // x[s][4k+3]
            }
            float z = bias + ((a0 + a1) + (a2 + a3));

            float a = (wave == 2) ? tanh_s(z) : sigm(z);

            float* gs = gate_s[s & 1];
            gs[tid] = a;                 // publish own gate
            __syncthreads();             // the one barrier per step

            // replicated c/h update (identical in all 4 waves)
            float i_ = gs[lane];
            float f_ = gs[64 + lane];
            float g_ = gs[128 + lane];
            float o_ = gs[192 + lane];
            c = f_ * c + i_ * g_;
            hreg = o_ * tanh_s(c);       // lane j: h[j] for next step
        }
    }

    // ---- epilogue: out[b] = h_T @ fc_w^T + fc_b ----
    __syncthreads();
    gate_s[0][lane] = hreg;              // all waves write identical values
    __syncthreads();
    if (tid < OUTN) {
        float acc = fc_b[tid];
        #pragma unroll
        for (int j = 0; j < Hh; ++j) acc += fc_w[tid * Hh + j] * gate_s[0][j];
        out[b * OUTN + tid] = acc;
    }
}

extern "C" void kernel_launch(void* const* d_in, const int* in_sizes, int n_in,
                              void* d_out, int out_size, void* d_ws, size_t ws_size,
                              hipStream_t stream) {
    const float* x    = (const float*)d_in[0];
    const float* w_ih = (const float*)d_in[1];
    const float* w_hh = (const float*)d_in[2];
    const float* b_ih = (const float*)d_in[3];
    const float* b_hh = (const float*)d_in[4];
    const float* fc_w = (const float*)d_in[5];
    const float* fc_b = (const float*)d_in[6];
    float* out = (float*)d_out;

    lstm_fused_kernel<<<Bb, 256, 0, stream>>>(x, w_ih, w_hh, b_ih, b_hh,
                                              fc_w, fc_b, out);
}

// Round 4
// 1735.366 us; speedup vs baseline: 1.4098x; 1.4098x over previous
//
#include <hip/hip_runtime.h>
#include <math.h>

// LSTM B=256, T=2048, D=H=64, OUT=8, fp32. One block per batch row.
// Round-4: K-SPLIT BROADCAST. Round 2/3 post-mortems show the step cost is
// LDS-pipe issue: 4 waves each broadcasting all 128 operands = 128 b128/step
// (1536 cyc, == measured 1630). Fix: wave w reads ONLY its 32-float k-slice
// (8 b128 broadcast), computes partial dots for all 256 rows (4 rows/lane,
// k-slice weights pinned in 128 regs/lane), partials reduced via LDS.
// LDS/step: 32 b128 + ~44 small ops ~= 670 cyc (2.5x less than round 2).
// Wave w reduces rows 64w+lane == tid -> gate type w (i,f,g,o order).
// c/h update replicated in all waves; h republished to LDS for next step.

#define Hh 64
#define Tt 2048
#define Bb 256
#define OUTN 8
#define CHUNK 64
#define NCHUNK (Tt / CHUNK)

typedef float floatx4 __attribute__((ext_vector_type(4)));

__device__ __forceinline__ float sigm(float z) {
    return 1.0f / (1.0f + __expf(-z));
}
__device__ __forceinline__ float tanh_s(float z) {   // overflow-safe tanh
    float e = __expf(2.0f * fabsf(z));
    float r = 1.0f - 2.0f / (e + 1.0f);
    return (z < 0.0f) ? -r : r;
}

__global__ __launch_bounds__(256, 1)
void lstm_fused_kernel(const float* __restrict__ x,
                       const float* __restrict__ w_ih,
                       const float* __restrict__ w_hh,
                       const float* __restrict__ b_ih,
                       const float* __restrict__ b_hh,
                       const float* __restrict__ fc_w,
                       const float* __restrict__ fc_b,
                       float* __restrict__ out)
{
    __shared__ __align__(16) float xch[2][CHUNK * Hh];  // 2 x 16 KB x chunks
    __shared__ __align__(16) float P[4][256];           // per-wave partials
    __shared__ float gate_s[256];                       // activated i,f,g,o
    __shared__ __align__(16) float h_s[Hh];             // hidden state

    const int tid  = threadIdx.x;
    const int b    = blockIdx.x;
    const int wave = tid >> 6;       // k-slice owner; also gate type in reduce
    const int lane = tid & 63;

    const float* xb = x + (size_t)b * Tt * Hh;

    // ---- weights: lane owns rows 4*lane..4*lane+3, k-slice [32*wave, +32).
    // k<64 -> w_ih (waves 0,1); k>=64 -> w_hh (waves 2,3). Pinned via asm.
    floatx4 wv[4][8];
    {
        const float* Wsrc = (wave < 2) ? w_ih : w_hh;
        const int kbase = 32 * (wave & 1);
        #pragma unroll
        for (int r = 0; r < 4; ++r) {
            const floatx4* p = (const floatx4*)(Wsrc + (size_t)(4 * lane + r) * Hh + kbase);
            #pragma unroll
            for (int q = 0; q < 8; ++q) wv[r][q] = p[q];
        }
        #pragma unroll
        for (int r = 0; r < 4; ++r)
            #pragma unroll
            for (int q = 0; q < 8; ++q)
                asm volatile("" : "+v"(wv[r][q]));
    }
    const float bias = b_ih[tid] + b_hh[tid];   // row 64*wave+lane == tid

    // ---- stage chunk 0 (async), zero h ----
    #pragma unroll
    for (int p4 = 0; p4 < 4; ++p4) {
        __builtin_amdgcn_global_load_lds(
            (const __attribute__((address_space(1))) void*)(xb + p4 * 1024 + tid * 4),
            (__attribute__((address_space(3))) void*)(&xch[0][p4 * 1024 + tid * 4]),
            16, 0, 0);
    }
    if (tid < Hh) h_s[tid] = 0.0f;
    float c = 0.0f;   // lane j of every wave holds c[j] (replicated)
    __syncthreads();

    for (int cc = 0; cc < NCHUNK; ++cc) {
        if (cc + 1 < NCHUNK) {       // async-stage next chunk
            const float* src = xb + (size_t)(cc + 1) * CHUNK * Hh;
            float* dst = &xch[(cc + 1) & 1][0];
            #pragma unroll
            for (int p4 = 0; p4 < 4; ++p4) {
                __builtin_amdgcn_global_load_lds(
                    (const __attribute__((address_space(1))) void*)(src + p4 * 1024 + tid * 4),
                    (__attribute__((address_space(3))) void*)(dst + p4 * 1024 + tid * 4),
                    16, 0, 0);
            }
        }
        const float* xcbuf = &xch[cc & 1][0];

        for (int s = 0; s < CHUNK; ++s) {
            // ---- broadcast-read ONLY this wave's 32-float operand slice ----
            // waves 0,1: x_t[0:32), x_t[32:64);  waves 2,3: h[0:32), h[32:64)
            const floatx4* opsrc = (wave < 2)
                ? (const floatx4*)(xcbuf + s * Hh + 32 * (wave & 1))
                : (const floatx4*)(h_s + 32 * (wave & 1));
            floatx4 op[8];
            #pragma unroll
            for (int q = 0; q < 8; ++q) op[q] = opsrc[q];

            // ---- partial dots: 4 rows x 32 k, vector FMA ----
            floatx4 va0 = {0,0,0,0}, va1 = {0,0,0,0}, va2 = {0,0,0,0}, va3 = {0,0,0,0};
            #pragma unroll
            for (int q = 0; q < 8; ++q) {
                floatx4 o4 = op[q];
                va0 += wv[0][q] * o4;
                va1 += wv[1][q] * o4;
                va2 += wv[2][q] * o4;
                va3 += wv[3][q] * o4;
            }
            floatx4 part;
            part.x = (va0.x + va0.y) + (va0.z + va0.w);
            part.y = (va1.x + va1.y) + (va1.z + va1.w);
            part.z = (va2.x + va2.y) + (va2.z + va2.w);
            part.w = (va3.x + va3.y) + (va3.z + va3.w);
            *(floatx4*)&P[wave][4 * lane] = part;     // rows 4*lane..+3
            __syncthreads();                          // B1: partials ready

            // ---- reduce + activate: this thread owns gate row `tid` ----
            float z = bias + ((P[0][tid] + P[1][tid]) + (P[2][tid] + P[3][tid]));
            float a = (wave == 2) ? tanh_s(z) : sigm(z);
            gate_s[tid] = a;
            __syncthreads();                          // B2: gates ready

            // ---- replicated c/h update (identical in all 4 waves) ----
            float i_ = gate_s[lane];
            float f_ = gate_s[64 + lane];
            float g_ = gate_s[128 + lane];
            float o_ = gate_s[192 + lane];
            c = f_ * c + i_ * g_;
            float hnew = o_ * tanh_s(c);
            h_s[lane] = hnew;        // benign same-value race across waves
            __syncthreads();                          // B3: h ready
        }
    }

    // ---- epilogue: out[b] = h_T @ fc_w^T + fc_b  (h_s holds h_T) ----
    if (tid < OUTN) {
        float acc = fc_b[tid];
        #pragma unroll
        for (int j = 0; j < Hh; ++j) acc += fc_w[tid * Hh + j] * h_s[j];
        out[b * OUTN + tid] = acc;
    }
}

extern "C" void kernel_launch(void* const* d_in, const int* in_sizes, int n_in,
                              void* d_out, int out_size, void* d_ws, size_t ws_size,
                              hipStream_t stream) {
    const float* x    = (const float*)d_in[0];
    const float* w_ih = (const float*)d_in[1];
    const float* w_hh = (const float*)d_in[2];
    const float* b_ih = (const float*)d_in[3];
    const float* b_hh = (const float*)d_in[4];
    const float* fc_w = (const float*)d_in[5];
    const float* fc_b = (const float*)d_in[6];
    float* out = (float*)d_out;

    lstm_fused_kernel<<<Bb, 256, 0, stream>>>(x, w_ih, w_hh, b_ih, b_hh,
                                              fc_w, fc_b, out);
}

// Round 5
// 1265.788 us; speedup vs baseline: 1.9328x; 1.3710x over previous
//
#include <hip/hip_runtime.h>
#include <math.h>

// LSTM B=256, T=2048, D=H=64, OUT=8, fp32. One block (4 waves) per batch row.
// Round-5: ONE-BARRIER STEP. Round-4 post-mortem: step is latency-bound on
// 3 barrier round-trips (~350 cyc each), not LDS/VALU throughput.
// New decomposition: lane j owns hidden unit j; wave w owns k-slice
// [16w,16w+16) of x AND [16w,16w+16) of h. Each lane computes 4-gate
// partials (rows j,64+j,128+j,192+j) over its wave's slice (128 pinned
// weight VGPRs), writes ONE b128 partial, ONE barrier, then reads 4 b128
// partials and does reduce + 4 activations + c/h update ALL IN REGISTERS.
// h exchange is wave-local (every wave writes all 64 h -> replicated),
// so no second barrier; P is parity-double-buffered to avoid WAR hazard.
// x chunk prefetch clustered at s==63 so only 1 barrier/64 steps pays the
// s_waitcnt vmcnt(0) drain that __syncthreads implies.

#define Hh 64
#define Tt 2048
#define Bb 256
#define OUTN 8
#define CHUNK 64
#define NCHUNK (Tt / CHUNK)

typedef float floatx4 __attribute__((ext_vector_type(4)));

__device__ __forceinline__ float sigm(float z) {
    return 1.0f / (1.0f + __expf(-z));
}
__device__ __forceinline__ float tanh_s(float z) {   // overflow-safe tanh
    float e = __expf(2.0f * fabsf(z));
    float r = 1.0f - 2.0f / (e + 1.0f);
    return (z < 0.0f) ? -r : r;
}
__device__ __forceinline__ float hsum4(floatx4 a) {
    return (a.x + a.y) + (a.z + a.w);
}

__global__ __launch_bounds__(256, 1)
void lstm_fused_kernel(const float* __restrict__ x,
                       const float* __restrict__ w_ih,
                       const float* __restrict__ w_hh,
                       const float* __restrict__ b_ih,
                       const float* __restrict__ b_hh,
                       const float* __restrict__ fc_w,
                       const float* __restrict__ fc_b,
                       float* __restrict__ out)
{
    __shared__ __align__(16) float xch[2][CHUNK * Hh];   // 2 x 16 KB x chunks
    __shared__ __align__(16) float P[2][4][Hh][4];       // parity x wave x j x gate
    __shared__ __align__(16) float h_s[Hh];

    const int tid  = threadIdx.x;
    const int b    = blockIdx.x;
    const int wave = tid >> 6;     // k-slice index
    const int lane = tid & 63;     // hidden unit j

    const float* xb = x + (size_t)b * Tt * Hh;

    // ---- weights: lane j, gate g -> row 64g+j, cols [16*wave, 16*wave+16) ----
    floatx4 wx[4][4], wh[4][4];    // 32 float4 = 128 VGPRs, pinned
    {
        const int kb = 16 * wave;
        #pragma unroll
        for (int g = 0; g < 4; ++g) {
            const floatx4* pi = (const floatx4*)(w_ih + (size_t)((g << 6) + lane) * Hh + kb);
            const floatx4* ph = (const floatx4*)(w_hh + (size_t)((g << 6) + lane) * Hh + kb);
            #pragma unroll
            for (int q = 0; q < 4; ++q) { wx[g][q] = pi[q]; wh[g][q] = ph[q]; }
        }
        #pragma unroll
        for (int g = 0; g < 4; ++g)
            #pragma unroll
            for (int q = 0; q < 4; ++q)
                asm volatile("" : "+v"(wx[g][q]), "+v"(wh[g][q]));
    }
    floatx4 bias4;
    bias4.x = b_ih[lane]       + b_hh[lane];         // i
    bias4.y = b_ih[64 + lane]  + b_hh[64 + lane];    // f
    bias4.z = b_ih[128 + lane] + b_hh[128 + lane];   // g
    bias4.w = b_ih[192 + lane] + b_hh[192 + lane];   // o

    // ---- stage chunk 0 (async; drained by the init barrier), zero h ----
    #pragma unroll
    for (int p4 = 0; p4 < 4; ++p4) {
        __builtin_amdgcn_global_load_lds(
            (const __attribute__((address_space(1))) void*)(xb + p4 * 1024 + tid * 4),
            (__attribute__((address_space(3))) void*)(&xch[0][p4 * 1024 + tid * 4]),
            16, 0, 0);
    }
    if (tid < Hh) h_s[tid] = 0.0f;
    float c = 0.0f;                // lane j of every wave: c[j] (replicated)
    __syncthreads();

    for (int cc = 0; cc < NCHUNK; ++cc) {
        const float* xcbuf = &xch[cc & 1][0];

        #pragma unroll 2
        for (int s = 0; s < CHUNK; ++s) {
            const int par = s & 1;

            // ---- partial dots over this wave's 32-k slice (x then h) ----
            const floatx4* xs = (const floatx4*)(xcbuf + s * Hh + 16 * wave);
            const floatx4* hs = (const floatx4*)(h_s + 16 * wave);
            floatx4 a0 = {0,0,0,0}, a1 = {0,0,0,0}, a2 = {0,0,0,0}, a3 = {0,0,0,0};
            #pragma unroll
            for (int q = 0; q < 4; ++q) {       // x half: no h dependency
                floatx4 v = xs[q];
                a0 += wx[0][q] * v; a1 += wx[1][q] * v;
                a2 += wx[2][q] * v; a3 += wx[3][q] * v;
            }
            #pragma unroll
            for (int q = 0; q < 4; ++q) {       // h half
                floatx4 v = hs[q];
                a0 += wh[0][q] * v; a1 += wh[1][q] * v;
                a2 += wh[2][q] * v; a3 += wh[3][q] * v;
            }
            floatx4 part;
            part.x = hsum4(a0); part.y = hsum4(a1);
            part.z = hsum4(a2); part.w = hsum4(a3);
            *(floatx4*)&P[par][wave][lane][0] = part;

            // cluster the next-chunk prefetch at the last step so only ONE
            // barrier per chunk pays the vmcnt(0) drain
            if (s == CHUNK - 1 && cc + 1 < NCHUNK) {
                const float* src = xb + (size_t)(cc + 1) * CHUNK * Hh;
                float* dst = &xch[(cc + 1) & 1][0];
                #pragma unroll
                for (int p4 = 0; p4 < 4; ++p4) {
                    __builtin_amdgcn_global_load_lds(
                        (const __attribute__((address_space(1))) void*)(src + p4 * 1024 + tid * 4),
                        (__attribute__((address_space(3))) void*)(dst + p4 * 1024 + tid * 4),
                        16, 0, 0);
                }
            }
            __syncthreads();                    // THE one barrier per step

            // ---- lane-local: reduce partials, activate, update c/h ----
            floatx4 z = bias4;
            #pragma unroll
            for (int w = 0; w < 4; ++w)
                z += *(const floatx4*)&P[par][w][lane][0];
            float i_ = sigm(z.x);
            float f_ = sigm(z.y);
            float g_ = tanh_s(z.z);
            float o_ = sigm(z.w);
            c = f_ * c + i_ * g_;
            float hnew = o_ * tanh_s(c);
            h_s[lane] = hnew;   // replicated same-value write by all 4 waves;
                                // next step's slice read is wave-local -> no barrier
        }
    }
    __syncthreads();

    // ---- epilogue: out[b] = h_T @ fc_w^T + fc_b ----
    if (tid < OUTN) {
        float acc = fc_b[tid];
        #pragma unroll
        for (int j = 0; j < Hh; ++j) acc += fc_w[tid * Hh + j] * h_s[j];
        out[b * OUTN + tid] = acc;
    }
}

extern "C" void kernel_launch(void* const* d_in, const int* in_sizes, int n_in,
                              void* d_out, int out_size, void* d_ws, size_t ws_size,
                              hipStream_t stream) {
    const float* x    = (const float*)d_in[0];
    const float* w_ih = (const float*)d_in[1];
    const float* w_hh = (const float*)d_in[2];
    const float* b_ih = (const float*)d_in[3];
    const float* b_hh = (const float*)d_in[4];
    const float* fc_w = (const float*)d_in[5];
    const float* fc_b = (const float*)d_in[6];
    float* out = (float*)d_out;

    lstm_fused_kernel<<<Bb, 256, 0, stream>>>(x, w_ih, w_hh, b_ih, b_hh,
                                              fc_w, fc_b, out);
}

// Round 6
// 990.162 us; speedup vs baseline: 2.4709x; 1.2784x over previous
//
#include <hip/hip_runtime.h>
#include <math.h>

// LSTM B=256, T=2048, D=H=64, OUT=8, fp32. One block (4 waves) per batch row.
// Round-6 on the round-5 one-barrier k-split skeleton:
//  (1) packed fp32 math (__builtin_elementwise_fma -> v_pk_fma_f32): FMA
//      issue halves vs round-5's scalar v_fma stream.
//  (2) gate logits pre-scaled by -log2e (g-gate: -2log2e) folded into the
//      weights+bias at load -> every activation is rcp(1+exp2(z')), tanh
//      as 2*sigma-1: no muls, no sign fixup, shorter serial act chain.
//  (3) software-pipelined x-dot: step s+1's x-contribution is computed
//      AFTER step s's barrier, between the P-reads and their use -> the
//      ~120 cyc P-read latency (round-5's naked stall) is covered by 16
//      independent pk-FMAs. Accumulators carry across the barrier.
//  Chunk staging issues right after the s==0 barrier (drain gets a full
//  step of cover; buffer WAR provably closed by the s==63 barrier).

#define Hh 64
#define Tt 2048
#define Bb 256
#define OUTN 8
#define CHUNK 64
#define NCHUNK (Tt / CHUNK)

typedef float floatx4 __attribute__((ext_vector_type(4)));
typedef float floatx2 __attribute__((ext_vector_type(2)));

__device__ __forceinline__ float hsum4(floatx4 a) {
    floatx2 t = a.lo + a.hi;          // v_pk_add_f32
    return t.x + t.y;
}

// sigma(z) given the PRE-SCALED logit zp = -log2e * z
__device__ __forceinline__ float sigm2(float zp) {
    return __builtin_amdgcn_rcpf(1.0f + __builtin_amdgcn_exp2f(zp));
}

__global__ __launch_bounds__(256, 1)
void lstm_fused_kernel(const float* __restrict__ x,
                       const float* __restrict__ w_ih,
                       const float* __restrict__ w_hh,
                       const float* __restrict__ b_ih,
                       const float* __restrict__ b_hh,
                       const float* __restrict__ fc_w,
                       const float* __restrict__ fc_b,
                       float* __restrict__ out)
{
    __shared__ __align__(16) float xch[2][CHUNK * Hh];   // 2 x 16 KB x chunks
    __shared__ __align__(16) float P[2][4][Hh][4];       // parity x wave x j x gate
    __shared__ __align__(16) float h_s[Hh];

    const int tid  = threadIdx.x;
    const int b    = blockIdx.x;
    const int wave = tid >> 6;     // k-slice index
    const int lane = tid & 63;     // hidden unit j

    const float* xb = x + (size_t)b * Tt * Hh;

    const float SC1 = -1.44269504088896340736f;   // -log2(e)
    const float SC2 = -2.88539008177792681472f;   // -2*log2(e)

    // ---- weights: lane j, gate g -> row 64g+j, cols [16w,16w+16), scaled ----
    floatx4 wx[4][4], wh[4][4];    // 32 float4 = 128 regs, pinned
    {
        const int kb = 16 * wave;
        #pragma unroll
        for (int g = 0; g < 4; ++g) {
            const float sc = (g == 2) ? SC2 : SC1;
            const floatx4* pi = (const floatx4*)(w_ih + (size_t)((g << 6) + lane) * Hh + kb);
            const floatx4* ph = (const floatx4*)(w_hh + (size_t)((g << 6) + lane) * Hh + kb);
            #pragma unroll
            for (int q = 0; q < 4; ++q) { wx[g][q] = pi[q] * sc; wh[g][q] = ph[q] * sc; }
        }
        #pragma unroll
        for (int g = 0; g < 4; ++g)
            #pragma unroll
            for (int q = 0; q < 4; ++q)
                asm volatile("" : "+v"(wx[g][q]), "+v"(wh[g][q]));
    }
    floatx4 bias4;
    bias4.x = (b_ih[lane]       + b_hh[lane])       * SC1;   // i
    bias4.y = (b_ih[64 + lane]  + b_hh[64 + lane])  * SC1;   // f
    bias4.z = (b_ih[128 + lane] + b_hh[128 + lane]) * SC2;   // g (tanh)
    bias4.w = (b_ih[192 + lane] + b_hh[192 + lane]) * SC1;   // o

    // ---- stage chunk 0 (async; drained by init barrier), zero h ----
    #pragma unroll
    for (int p4 = 0; p4 < 4; ++p4) {
        __builtin_amdgcn_global_load_lds(
            (const __attribute__((address_space(1))) void*)(xb + p4 * 1024 + tid * 4),
            (__attribute__((address_space(3))) void*)(&xch[0][p4 * 1024 + tid * 4]),
            16, 0, 0);
    }
    if (tid < Hh) h_s[tid] = 0.0f;
    float c = 0.0f;                // lane j of every wave: c[j] (replicated)
    __syncthreads();

    // ---- prime the pipeline: x-dot for (cc=0, s=0) ----
    floatx4 acc0, acc1, acc2, acc3;
    {
        const floatx4* xs = (const floatx4*)(&xch[0][16 * wave]);
        floatx4 v = xs[0];
        acc0 = wx[0][0] * v; acc1 = wx[1][0] * v;
        acc2 = wx[2][0] * v; acc3 = wx[3][0] * v;
        #pragma unroll
        for (int q = 1; q < 4; ++q) {
            v = xs[q];
            acc0 = __builtin_elementwise_fma(wx[0][q], v, acc0);
            acc1 = __builtin_elementwise_fma(wx[1][q], v, acc1);
            acc2 = __builtin_elementwise_fma(wx[2][q], v, acc2);
            acc3 = __builtin_elementwise_fma(wx[3][q], v, acc3);
        }
    }

    for (int cc = 0; cc < NCHUNK; ++cc) {
        const float* xcbuf = &xch[cc & 1][0];

        #pragma unroll 2
        for (int s = 0; s < CHUNK; ++s) {
            const int par = s & 1;

            // ---- h-half on the carried accumulators ----
            const floatx4* hs4 = (const floatx4*)(h_s + 16 * wave);
            #pragma unroll
            for (int q = 0; q < 4; ++q) {
                floatx4 v = hs4[q];
                acc0 = __builtin_elementwise_fma(wh[0][q], v, acc0);
                acc1 = __builtin_elementwise_fma(wh[1][q], v, acc1);
                acc2 = __builtin_elementwise_fma(wh[2][q], v, acc2);
                acc3 = __builtin_elementwise_fma(wh[3][q], v, acc3);
            }
            floatx4 part;
            part.x = hsum4(acc0); part.y = hsum4(acc1);
            part.z = hsum4(acc2); part.w = hsum4(acc3);
            *(floatx4*)&P[par][wave][lane][0] = part;
            __syncthreads();                 // THE one barrier per step

            // stage next chunk just AFTER the s==0 barrier: its vmcnt drain
            // (next barrier) is a full step away; consumed at s==63.
            if (s == 0 && cc + 1 < NCHUNK) {
                const float* src = xb + (size_t)(cc + 1) * CHUNK * Hh;
                float* dst = &xch[(cc + 1) & 1][0];
                #pragma unroll
                for (int p4 = 0; p4 < 4; ++p4) {
                    __builtin_amdgcn_global_load_lds(
                        (const __attribute__((address_space(1))) void*)(src + p4 * 1024 + tid * 4),
                        (__attribute__((address_space(3))) void*)(dst + p4 * 1024 + tid * 4),
                        16, 0, 0);
                }
            }

            // ---- P-reads; their latency is covered by next-step x-dot ----
            floatx4 p0 = *(const floatx4*)&P[par][0][lane][0];
            floatx4 p1 = *(const floatx4*)&P[par][1][lane][0];
            floatx4 p2 = *(const floatx4*)&P[par][2][lane][0];
            floatx4 p3 = *(const floatx4*)&P[par][3][lane][0];

            // next-step x-dot (independent of P). Last step of last chunk
            // reads a stale buffer: in-bounds, result discarded.
            const float* xn = (s + 1 < CHUNK) ? (xcbuf + (s + 1) * Hh)
                                              : &xch[(cc + 1) & 1][0];
            const floatx4* xs = (const floatx4*)(xn + 16 * wave);
            floatx4 n0, n1, n2, n3;
            {
                floatx4 v = xs[0];
                n0 = wx[0][0] * v; n1 = wx[1][0] * v;
                n2 = wx[2][0] * v; n3 = wx[3][0] * v;
            }
            #pragma unroll
            for (int q = 1; q < 4; ++q) {
                floatx4 v = xs[q];
                n0 = __builtin_elementwise_fma(wx[0][q], v, n0);
                n1 = __builtin_elementwise_fma(wx[1][q], v, n1);
                n2 = __builtin_elementwise_fma(wx[2][q], v, n2);
                n3 = __builtin_elementwise_fma(wx[3][q], v, n3);
            }

            // ---- reduce + activations (pre-scaled logits) + c/h update ----
            floatx4 z = bias4 + ((p0 + p1) + (p2 + p3));
            float i_ = sigm2(z.x);
            float f_ = sigm2(z.y);
            float g_ = 2.0f * sigm2(z.z) - 1.0f;      // tanh via 2*sigma-1
            float o_ = sigm2(z.w);
            c = __builtin_fmaf(f_, c, i_ * g_);
            float th = 2.0f * sigm2(SC2 * c) - 1.0f;
            h_s[lane] = o_ * th;     // replicated same-value write, all waves

            acc0 = n0; acc1 = n1; acc2 = n2; acc3 = n3;
        }
    }
    __syncthreads();

    // ---- epilogue: out[b] = h_T @ fc_w^T + fc_b ----
    if (tid < OUTN) {
        float acc = fc_b[tid];
        #pragma unroll
        for (int j = 0; j < Hh; ++j) acc += fc_w[tid * Hh + j] * h_s[j];
        out[b * OUTN + tid] = acc;
    }
}

extern "C" void kernel_launch(void* const* d_in, const int* in_sizes, int n_in,
                              void* d_out, int out_size, void* d_ws, size_t ws_size,
                              hipStream_t stream) {
    const float* x    = (const float*)d_in[0];
    const float* w_ih = (const float*)d_in[1];
    const float* w_hh = (const float*)d_in[2];
    const float* b_ih = (const float*)d_in[3];
    const float* b_hh = (const float*)d_in[4];
    const float* fc_w = (const float*)d_in[5];
    const float* fc_b = (const float*)d_in[6];
    float* out = (float*)d_out;

    lstm_fused_kernel<<<Bb, 256, 0, stream>>>(x, w_ih, w_hh, b_ih, b_hh,
                                              fc_w, fc_b, out);
}